// Round 1
// baseline (1567.745 us; speedup 1.0000x reference)
//
#include <hip/hip_runtime.h>
#include <math.h>

#define R_ROWS 49152      // B*N*S = 128*32*12
#define TR 12
#define HID 1024
#define SLOT 256
#define EMB 256
#define ACT 128
#define NCODE 1024
#define M_ROWS 47616      // B*(N-1)*S = 128*31*12

// output offsets (float elements)
#define OFF_AD 0
#define OFF_Z  12189696
#define OFF_AV 18284544
#define OFF_QS 24379392
#define OFF_IDX 30474240
#define OFF_QL 30521856
#define OFF_CL 30521857

// workspace offsets (float elements)
#define WS_MT   0
#define WS_VT   6291456
#define WS_PVAL 12582912
#define WS_PIDX 13344768
#define WS_LOSS 14106624

__global__ __launch_bounds__(256) void k_encoder(
    const float* __restrict__ X, const float* __restrict__ W1, const float* __restrict__ b1,
    const float* __restrict__ ln_g, const float* __restrict__ ln_b,
    const float* __restrict__ W2, const float* __restrict__ b2,
    const float* __restrict__ Wm, const float* __restrict__ bm,
    const float* __restrict__ Wv, const float* __restrict__ bv,
    float* __restrict__ MT, float* __restrict__ VT)
{
    __shared__ float Xs[TR][SLOT];   // 12x256, reused as E tile after GEMM2
    __shared__ float Hs[TR][HID];    // 12x1024
    __shared__ float mu_s[TR], rs_s[TR];

    const int tid = threadIdx.x;
    const int blk = blockIdx.x;
    const long rowbase = (long)blk * TR;

    // ---- load X tile (12x256) ----
    {
        const float4* Xg = (const float4*)(X + rowbase * SLOT);
        float4* Xs4 = (float4*)&Xs[0][0];
        #pragma unroll
        for (int i = 0; i < TR*SLOT/4/256; ++i)
            Xs4[tid + 256*i] = Xg[tid + 256*i];
    }
    __syncthreads();

    // ---- GEMM1: H = relu(X@W1 + b1); thread cols = tid + 256*cc ----
    float acc[4][TR];
    #pragma unroll
    for (int cc = 0; cc < 4; ++cc)
        #pragma unroll
        for (int r = 0; r < TR; ++r) acc[cc][r] = 0.f;

    for (int k = 0; k < SLOT; k += 4) {
        float4 xv[TR];
        #pragma unroll
        for (int r = 0; r < TR; ++r) xv[r] = *(const float4*)&Xs[r][k];
        #pragma unroll
        for (int kk = 0; kk < 4; ++kk) {
            const float* wrow = W1 + (size_t)(k+kk)*HID + tid;
            float w0 = wrow[0], w1 = wrow[256], w2 = wrow[512], w3 = wrow[768];
            #pragma unroll
            for (int r = 0; r < TR; ++r) {
                float x = ((const float*)&xv[r])[kk];
                acc[0][r] = fmaf(x, w0, acc[0][r]);
                acc[1][r] = fmaf(x, w1, acc[1][r]);
                acc[2][r] = fmaf(x, w2, acc[2][r]);
                acc[3][r] = fmaf(x, w3, acc[3][r]);
            }
        }
    }
    #pragma unroll
    for (int cc = 0; cc < 4; ++cc) {
        int col = tid + 256*cc;
        float bb = b1[col];
        #pragma unroll
        for (int r = 0; r < TR; ++r)
            Hs[r][col] = fmaxf(acc[cc][r] + bb, 0.f);
    }
    __syncthreads();

    // ---- LayerNorm stats: wave w handles rows 3w..3w+2 ----
    {
        const int lane = tid & 63;
        const int wv = tid >> 6;
        for (int rr = 0; rr < 3; ++rr) {
            int r = wv*3 + rr;
            float s = 0.f, sq = 0.f;
            #pragma unroll
            for (int i = 0; i < HID/64; ++i) {
                float v = Hs[r][lane + 64*i];
                s += v; sq = fmaf(v, v, sq);
            }
            #pragma unroll
            for (int off = 32; off; off >>= 1) {
                s  += __shfl_xor(s,  off, 64);
                sq += __shfl_xor(sq, off, 64);
            }
            if (lane == 0) {
                float mu = s * (1.f/HID);
                float var = sq * (1.f/HID) - mu*mu;
                mu_s[r] = mu;
                rs_s[r] = 1.f / sqrtf(var + 1e-5f);
            }
        }
    }
    __syncthreads();

    // ---- normalize in place ----
    {
        float* Hf = &Hs[0][0];
        #pragma unroll
        for (int j = 0; j < TR*HID/256; ++j) {
            int i = tid + 256*j;
            int r = i >> 10, c = i & (HID-1);
            Hf[i] = (Hf[i] - mu_s[r]) * rs_s[r] * ln_g[c] + ln_b[c];
        }
    }
    __syncthreads();

    // ---- GEMM2: E = Hn @ W2 + b2 (col = tid) ----
    float acc2[TR];
    #pragma unroll
    for (int r = 0; r < TR; ++r) acc2[r] = 0.f;
    for (int k = 0; k < HID; k += 4) {
        float4 hv[TR];
        #pragma unroll
        for (int r = 0; r < TR; ++r) hv[r] = *(const float4*)&Hs[r][k];
        #pragma unroll
        for (int kk = 0; kk < 4; ++kk) {
            float w = W2[(size_t)(k+kk)*EMB + tid];
            #pragma unroll
            for (int r = 0; r < TR; ++r)
                acc2[r] = fmaf(((const float*)&hv[r])[kk], w, acc2[r]);
        }
    }
    {
        float bb2 = b2[tid];
        #pragma unroll
        for (int r = 0; r < TR; ++r) Xs[r][tid] = acc2[r] + bb2;  // E tile
    }
    __syncthreads();

    // ---- heads: [MT | VT] = E @ [Wm | Wv] (+bias, abs on VT) ----
    float acc3[TR];
    #pragma unroll
    for (int r = 0; r < TR; ++r) acc3[r] = 0.f;
    const bool isv = (tid >= 128);
    const int jc = tid & 127;
    const float* Wx = isv ? Wv : Wm;
    for (int k = 0; k < EMB; k += 4) {
        float4 ev[TR];
        #pragma unroll
        for (int r = 0; r < TR; ++r) ev[r] = *(const float4*)&Xs[r][k];
        #pragma unroll
        for (int kk = 0; kk < 4; ++kk) {
            float w = Wx[(size_t)(k+kk)*ACT + jc];
            #pragma unroll
            for (int r = 0; r < TR; ++r)
                acc3[r] = fmaf(((const float*)&ev[r])[kk], w, acc3[r]);
        }
    }
    {
        float bx = isv ? bv[jc] : bm[jc];
        #pragma unroll
        for (int r = 0; r < TR; ++r) {
            float v = acc3[r] + bx;
            size_t o = (size_t)(rowbase + r)*ACT + jc;
            if (isv) VT[o] = fabsf(v);
            else     MT[o] = v;
        }
    }
}

__global__ __launch_bounds__(256) void k_action(
    const float* __restrict__ MT, const float* __restrict__ VT,
    const float* __restrict__ noise, float* __restrict__ out)
{
    int gid = blockIdx.x*256 + threadIdx.x;           // M_ROWS*ACT total
    int a = gid & 127;
    int m = gid >> 7;
    int s  = m % 12;
    int bn = m / 12;
    int n = bn % 31;
    int b = bn / 31;
    int r1 = (b*32 + n)*12 + s;
    int r2 = r1 + 12;
    float m1 = MT[(size_t)r1*ACT + a], m2 = MT[(size_t)r2*ACT + a];
    float v1 = VT[(size_t)r1*ACT + a], v2 = VT[(size_t)r2*ACT + a];
    float adm = m2 - m1;
    float adv = v2 + v1;
    float nz = noise[gid];
    float z = nz * sqrtf(adv + 1e-6f) + adm;
    size_t adbase = ((((size_t)(b*31 + n)*2 + 0)*12 + s)*ACT) + a;
    out[OFF_AD + adbase] = adm;
    out[OFF_AD + adbase + 12*ACT] = adv;
    out[OFF_Z + gid] = z;
}

// distances (drop |z|^2 row-constant): d = |c|^2 - 2 z.c ; partial argmin per 64-code block
__global__ __launch_bounds__(256) void k_vq_part(
    const float* __restrict__ Zg, const float* __restrict__ CB,
    float* __restrict__ pval, int* __restrict__ pidx)
{
    __shared__ float Zs[64][128];      // 32 KB
    __shared__ float CsT[128][64];     // 32 KB (k-major)

    const int bi = blockIdx.x;
    const int rb = bi >> 4;            // 0..743
    const int cb = bi & 15;            // code block (64 codes)
    const int tid = threadIdx.x;

    // load z tile (64x128)
    {
        const float4* zsrc = (const float4*)(Zg + (size_t)rb*64*ACT);
        float4* zd = (float4*)&Zs[0][0];
        #pragma unroll
        for (int j = 0; j < 64*ACT/4/256; ++j)
            zd[tid + 256*j] = zsrc[tid + 256*j];
    }
    // load codebook chunk transposed
    #pragma unroll
    for (int j = 0; j < 64*ACT/4/256; ++j) {
        int i = tid + 256*j;
        int c = i & 63;
        int kq = i >> 6;               // 0..31
        float4 v = *(const float4*)&CB[(size_t)(cb*64 + c)*ACT + kq*4];
        CsT[kq*4+0][c] = v.x; CsT[kq*4+1][c] = v.y;
        CsT[kq*4+2][c] = v.z; CsT[kq*4+3][c] = v.w;
    }
    __syncthreads();

    const int rg = tid >> 4;           // rows rg*4..+3
    const int cg = tid & 15;           // codes cg*4..+3
    float dot[4][4];
    float cn[4] = {0.f, 0.f, 0.f, 0.f};
    #pragma unroll
    for (int i = 0; i < 4; ++i)
        #pragma unroll
        for (int j = 0; j < 4; ++j) dot[i][j] = 0.f;

    for (int k = 0; k < ACT; k += 4) {
        float4 zv[4];
        #pragma unroll
        for (int i = 0; i < 4; ++i) zv[i] = *(const float4*)&Zs[rg*4 + i][k];
        float4 cv[4];
        #pragma unroll
        for (int kk = 0; kk < 4; ++kk) cv[kk] = *(const float4*)&CsT[k + kk][cg*4];
        #pragma unroll
        for (int kk = 0; kk < 4; ++kk) {
            float4 c4 = cv[kk];
            cn[0] = fmaf(c4.x, c4.x, cn[0]);
            cn[1] = fmaf(c4.y, c4.y, cn[1]);
            cn[2] = fmaf(c4.z, c4.z, cn[2]);
            cn[3] = fmaf(c4.w, c4.w, cn[3]);
            #pragma unroll
            for (int i = 0; i < 4; ++i) {
                float zz = ((const float*)&zv[i])[kk];
                dot[i][0] = fmaf(zz, c4.x, dot[i][0]);
                dot[i][1] = fmaf(zz, c4.y, dot[i][1]);
                dot[i][2] = fmaf(zz, c4.z, dot[i][2]);
                dot[i][3] = fmaf(zz, c4.w, dot[i][3]);
            }
        }
    }

    #pragma unroll
    for (int i = 0; i < 4; ++i) {
        float best = cn[0] - 2.f*dot[i][0];
        int bidx = cb*64 + cg*4;
        #pragma unroll
        for (int j = 1; j < 4; ++j) {
            float d = cn[j] - 2.f*dot[i][j];
            int gi = cb*64 + cg*4 + j;
            if (d < best) { best = d; bidx = gi; }
        }
        // reduce over the 16 cg lanes (low 4 bits of lane id)
        #pragma unroll
        for (int off = 1; off < 16; off <<= 1) {
            float ov = __shfl_xor(best, off, 64);
            int   oi = __shfl_xor(bidx, off, 64);
            if (ov < best || (ov == best && oi < bidx)) { best = ov; bidx = oi; }
        }
        if (cg == 0) {
            size_t m = (size_t)rb*64 + rg*4 + i;
            pval[m*16 + cb] = best;
            pidx[m*16 + cb] = bidx;
        }
    }
}

__global__ __launch_bounds__(256) void k_finalize(
    const float* __restrict__ pval, const int* __restrict__ pidx,
    const float* __restrict__ CB, float* __restrict__ out, float* __restrict__ losss)
{
    __shared__ int idx_s[2];
    __shared__ float red[4];
    const int t = threadIdx.x;
    const int half = t >> 7;
    const int a = t & 127;
    const size_t m = (size_t)blockIdx.x*2 + half;

    if (a == 0) {
        const float* pv = &pval[m*16];
        const int*   pi = &pidx[m*16];
        float best = pv[0]; int bi = pi[0];
        for (int i = 1; i < 16; ++i) {
            float v = pv[i]; int ii = pi[i];
            if (v < best || (v == best && ii < bi)) { best = v; bi = ii; }
        }
        idx_s[half] = bi;
        out[OFF_IDX + m] = (float)bi;
    }
    __syncthreads();

    int ci = idx_s[half];
    float q = CB[(size_t)ci*ACT + a];
    float z = out[OFF_Z + m*ACT + a];
    float diff = z - q;
    out[OFF_QS + m*ACT + a] = z + (q - z);
    out[OFF_AV + m*ACT + a] = diff;

    float ls = diff*diff;
    #pragma unroll
    for (int off = 32; off; off >>= 1) ls += __shfl_xor(ls, off, 64);
    if ((t & 63) == 0) red[t >> 6] = ls;
    __syncthreads();
    if (t == 0) atomicAdd(losss, red[0] + red[1] + red[2] + red[3]);
}

__global__ void k_init(float* losss) { *losss = 0.f; }

__global__ void k_losses(const float* __restrict__ losss, float* __restrict__ out)
{
    float v = *losss * (1.f / 6094848.f);
    out[OFF_QL] = v;
    out[OFF_CL] = v;
}

extern "C" void kernel_launch(void* const* d_in, const int* in_sizes, int n_in,
                              void* d_out, int out_size, void* d_ws, size_t ws_size,
                              hipStream_t stream)
{
    const float* slots = (const float*)d_in[0];
    const float* noise = (const float*)d_in[1];
    const float* W1    = (const float*)d_in[2];
    const float* b1    = (const float*)d_in[3];
    const float* ln_g  = (const float*)d_in[4];
    const float* ln_b  = (const float*)d_in[5];
    const float* W2    = (const float*)d_in[6];
    const float* b2    = (const float*)d_in[7];
    const float* Wm    = (const float*)d_in[8];
    const float* bm    = (const float*)d_in[9];
    const float* Wv    = (const float*)d_in[10];
    const float* bv    = (const float*)d_in[11];
    const float* CB    = (const float*)d_in[12];
    float* out = (float*)d_out;
    float* ws  = (float*)d_ws;

    float* MT   = ws + WS_MT;
    float* VT   = ws + WS_VT;
    float* pval = ws + WS_PVAL;
    int*   pidx = (int*)(ws + WS_PIDX);
    float* losss = ws + WS_LOSS;

    hipLaunchKernelGGL(k_init, dim3(1), dim3(1), 0, stream, losss);
    hipLaunchKernelGGL(k_encoder, dim3(R_ROWS/TR), dim3(256), 0, stream,
                       slots, W1, b1, ln_g, ln_b, W2, b2, Wm, bm, Wv, bv, MT, VT);
    hipLaunchKernelGGL(k_action, dim3(M_ROWS*ACT/256), dim3(256), 0, stream,
                       MT, VT, noise, out);
    hipLaunchKernelGGL(k_vq_part, dim3((M_ROWS/64)*16), dim3(256), 0, stream,
                       out + OFF_Z, CB, pval, pidx);
    hipLaunchKernelGGL(k_finalize, dim3(M_ROWS/2), dim3(256), 0, stream,
                       pval, pidx, CB, out, losss);
    hipLaunchKernelGGL(k_losses, dim3(1), dim3(1), 0, stream, losss, out);
}

// Round 2
// 978.642 us; speedup vs baseline: 1.6020x; 1.6020x over previous
//
#include <hip/hip_runtime.h>
#include <math.h>

#define R_ROWS 49152      // B*N*S = 128*32*12
#define HID 1024
#define SLOT 256
#define EMB 256
#define ACT 128
#define NCODE 1024
#define M_ROWS 47616      // B*(N-1)*S = 128*31*12

// output offsets (float elements)
#define OFF_AD 0
#define OFF_Z  12189696
#define OFF_AV 18284544
#define OFF_QS 24379392
#define OFF_IDX 30474240
#define OFF_QL 30521856
#define OFF_CL 30521857

// workspace offsets (float elements)
#define WS_MT   0
#define WS_VT   6291456
#define WS_PVAL 12582912
#define WS_PIDX 13344768
#define WS_LOSS 14106624
// packed fp16x2 weights overlap the PVAL/PIDX region: they are consumed by
// k_encoder_mfma, which completes before k_vq_part writes pval/pidx.
#define WS_W1H 12582912
#define WS_W1L 12713984
#define WS_W2H 12845056
#define WS_W2L 12976128
#define WS_WMH 13107200
#define WS_WML 13123584
#define WS_WVH 13139968
#define WS_WVL 13156352

typedef _Float16 f16x8 __attribute__((ext_vector_type(8)));
typedef float f32x4 __attribute__((ext_vector_type(4)));

// Pack a K x N fp32 matrix into MFMA B-fragment-linear fp16 hi/lo arrays.
// For n-tile t (16 cols), k-step s (32), lane l, j in 0..7:
//   packed[((t*S + s)*64 + l)*8 + j] = W[s*32 + (l>>4)*8 + j][t*16 + (l&15)]
__global__ __launch_bounds__(256) void k_pack(
    const float* __restrict__ W, _Float16* __restrict__ hi, _Float16* __restrict__ lo,
    int lgS, int N)
{
    int p = blockIdx.x * 256 + threadIdx.x;
    int j = p & 7;
    int l = (p >> 3) & 63;
    int q = p >> 9;
    int s = q & ((1 << lgS) - 1);
    int t = q >> lgS;
    int n = t * 16 + (l & 15);
    int k = s * 32 + ((l >> 4) << 3) + j;
    float x = W[(size_t)k * N + n];
    _Float16 h = (_Float16)x;
    hi[p] = h;
    lo[p] = (_Float16)(x - (float)h);
}

__global__ __launch_bounds__(256, 2) void k_encoder_mfma(
    const float* __restrict__ X,
    const float* __restrict__ b1, const float* __restrict__ ln_g, const float* __restrict__ ln_b,
    const float* __restrict__ b2, const float* __restrict__ bm, const float* __restrict__ bv,
    const _Float16* __restrict__ W1h, const _Float16* __restrict__ W1l,
    const _Float16* __restrict__ W2h, const _Float16* __restrict__ W2l,
    const _Float16* __restrict__ Wmh, const _Float16* __restrict__ Wml,
    const _Float16* __restrict__ Wvh, const _Float16* __restrict__ Wvl,
    float* __restrict__ MT, float* __restrict__ VT)
{
    __shared__ _Float16 Hh0[16][1024];   // 32 KB (hi), also aliased for stats + E tile
    __shared__ _Float16 Hh1[16][1024];   // 32 KB (lo)

    const int tid = threadIdx.x;
    const int w  = tid >> 6;
    const int l  = tid & 63;
    const int lr = l & 15;
    const int lg = l >> 4;
    const long rowbase = (long)blockIdx.x * 16;

    // ---- A fragments for GEMM1: 16 rows x 256 k, fp16 hi/lo in registers ----
    f16x8 a0[8], a1[8];
    {
        const float* xrow = X + (rowbase + lr) * SLOT + lg * 8;
        #pragma unroll
        for (int s = 0; s < 8; ++s) {
            float4 xa = *(const float4*)(xrow + 32 * s);
            float4 xb = *(const float4*)(xrow + 32 * s + 4);
            float xv[8] = {xa.x, xa.y, xa.z, xa.w, xb.x, xb.y, xb.z, xb.w};
            #pragma unroll
            for (int e = 0; e < 8; ++e) {
                _Float16 h = (_Float16)xv[e];
                a0[s][e] = h;
                a1[s][e] = (_Float16)(xv[e] - (float)h);
            }
        }
    }

    // ---- GEMM1: H = X @ W1 (fp16x2, 3 passes), wave w owns cols [256w, 256w+256) ----
    f32x4 acc[16];
    #pragma unroll
    for (int t = 0; t < 16; ++t) acc[t] = (f32x4){0.f, 0.f, 0.f, 0.f};

    #pragma unroll
    for (int s = 0; s < 8; ++s) {
        #pragma unroll
        for (int t = 0; t < 16; ++t) {
            int tg = w * 16 + t;
            f16x8 bh = *(const f16x8*)(W1h + ((size_t)(tg * 8 + s) * 64 + l) * 8);
            f16x8 bl = *(const f16x8*)(W1l + ((size_t)(tg * 8 + s) * 64 + l) * 8);
            acc[t] = __builtin_amdgcn_mfma_f32_16x16x32_f16(a0[s], bh, acc[t], 0, 0, 0);
            acc[t] = __builtin_amdgcn_mfma_f32_16x16x32_f16(a0[s], bl, acc[t], 0, 0, 0);
            acc[t] = __builtin_amdgcn_mfma_f32_16x16x32_f16(a1[s], bh, acc[t], 0, 0, 0);
        }
    }

    // ---- bias + ReLU on accumulators ----
    #pragma unroll
    for (int t = 0; t < 16; ++t) {
        float bb = b1[w * 256 + t * 16 + lr];
        #pragma unroll
        for (int r = 0; r < 4; ++r) acc[t][r] = fmaxf(acc[t][r] + bb, 0.f);
    }

    // ---- LayerNorm stats: per-lane partial over 16 tiles, reduce over 16-lane group,
    //      cross-wave via LDS (aliased over Hh0, which is not yet written) ----
    float sum[4] = {0,0,0,0}, sq[4] = {0,0,0,0};
    #pragma unroll
    for (int t = 0; t < 16; ++t)
        #pragma unroll
        for (int r = 0; r < 4; ++r) {
            float v = acc[t][r];
            sum[r] += v; sq[r] = fmaf(v, v, sq[r]);
        }
    #pragma unroll
    for (int off = 1; off < 16; off <<= 1)
        #pragma unroll
        for (int r = 0; r < 4; ++r) {
            sum[r] += __shfl_xor(sum[r], off, 64);
            sq[r]  += __shfl_xor(sq[r],  off, 64);
        }
    float* stat = (float*)&Hh0[0][0];    // [0..63]=sum partials, [64..127]=sq partials
    if (lr == 0) {
        #pragma unroll
        for (int r = 0; r < 4; ++r) {
            stat[w * 16 + 4 * lg + r]      = sum[r];
            stat[64 + w * 16 + 4 * lg + r] = sq[r];
        }
    }
    __syncthreads();
    float mu[4], rs[4];
    #pragma unroll
    for (int r = 0; r < 4; ++r) {
        int m = 4 * lg + r;
        float s = stat[m] + stat[16 + m] + stat[32 + m] + stat[48 + m];
        float q = stat[64 + m] + stat[80 + m] + stat[96 + m] + stat[112 + m];
        float mmu = s * (1.f / HID);
        float var = q * (1.f / HID) - mmu * mmu;
        mu[r] = mmu;
        rs[r] = 1.f / sqrtf(var + 1e-5f);
    }
    __syncthreads();   // stats reads done before Hh0 is overwritten

    // ---- normalize, split to fp16 hi/lo, write swizzled into LDS ----
    #pragma unroll
    for (int t = 0; t < 16; ++t) {
        int n = w * 256 + t * 16 + lr;
        float g = ln_g[n], be = ln_b[n];
        #pragma unroll
        for (int r = 0; r < 4; ++r) {
            int m = 4 * lg + r;
            float v = (acc[t][r] - mu[r]) * rs[r] * g + be;
            _Float16 h = (_Float16)v;
            _Float16 lo = (_Float16)(v - (float)h);
            int c = n >> 3, jj = n & 7;
            int cs = c ^ (m & 7);
            Hh0[m][cs * 8 + jj] = h;
            Hh1[m][cs * 8 + jj] = lo;
        }
    }
    __syncthreads();

    // ---- GEMM2: E = Hn @ W2, wave w owns cols [64w, 64w+64) ----
    f32x4 acc2[4];
    #pragma unroll
    for (int t = 0; t < 4; ++t) acc2[t] = (f32x4){0.f, 0.f, 0.f, 0.f};

    #pragma unroll 4
    for (int s = 0; s < 32; ++s) {
        int cs = (4 * s + lg) ^ (lr & 7);
        f16x8 ah = *(const f16x8*)&Hh0[lr][cs * 8];
        f16x8 al = *(const f16x8*)&Hh1[lr][cs * 8];
        #pragma unroll
        for (int t = 0; t < 4; ++t) {
            int tg = w * 4 + t;
            f16x8 bh = *(const f16x8*)(W2h + ((size_t)(tg * 32 + s) * 64 + l) * 8);
            f16x8 bl = *(const f16x8*)(W2l + ((size_t)(tg * 32 + s) * 64 + l) * 8);
            acc2[t] = __builtin_amdgcn_mfma_f32_16x16x32_f16(ah, bh, acc2[t], 0, 0, 0);
            acc2[t] = __builtin_amdgcn_mfma_f32_16x16x32_f16(ah, bl, acc2[t], 0, 0, 0);
            acc2[t] = __builtin_amdgcn_mfma_f32_16x16x32_f16(al, bh, acc2[t], 0, 0, 0);
        }
    }
    __syncthreads();   // all GEMM2 LDS reads done before E overwrites Hh0

    // ---- E tile (+b2) -> fp16x2, swizzled, aliased into Hh0 ----
    _Float16* Es0 = &Hh0[0][0];          // 16x256
    _Float16* Es1 = &Hh0[0][0] + 4096;   // 16x256
    #pragma unroll
    for (int t = 0; t < 4; ++t) {
        int n = w * 64 + t * 16 + lr;
        float bb2 = b2[n];
        #pragma unroll
        for (int r = 0; r < 4; ++r) {
            int m = 4 * lg + r;
            float v = acc2[t][r] + bb2;
            _Float16 h = (_Float16)v;
            _Float16 lo = (_Float16)(v - (float)h);
            int c = n >> 3, jj = n & 7;
            int cs = c ^ (m & 7);
            Es0[m * 256 + cs * 8 + jj] = h;
            Es1[m * 256 + cs * 8 + jj] = lo;
        }
    }
    __syncthreads();

    // ---- heads: waves 0,1 -> MT (Wm), waves 2,3 -> VT (Wv, abs) ----
    const _Float16* WXh = (w < 2) ? Wmh : Wvh;
    const _Float16* WXl = (w < 2) ? Wml : Wvl;
    f32x4 acc3[4];
    #pragma unroll
    for (int t = 0; t < 4; ++t) acc3[t] = (f32x4){0.f, 0.f, 0.f, 0.f};

    #pragma unroll
    for (int s = 0; s < 8; ++s) {
        int cs = (4 * s + lg) ^ (lr & 7);
        f16x8 ah = *(const f16x8*)&Es0[lr * 256 + cs * 8];
        f16x8 al = *(const f16x8*)&Es1[lr * 256 + cs * 8];
        #pragma unroll
        for (int t = 0; t < 4; ++t) {
            int tg = (w & 1) * 4 + t;
            f16x8 bh = *(const f16x8*)(WXh + ((size_t)(tg * 8 + s) * 64 + l) * 8);
            f16x8 bl = *(const f16x8*)(WXl + ((size_t)(tg * 8 + s) * 64 + l) * 8);
            acc3[t] = __builtin_amdgcn_mfma_f32_16x16x32_f16(ah, bh, acc3[t], 0, 0, 0);
            acc3[t] = __builtin_amdgcn_mfma_f32_16x16x32_f16(ah, bl, acc3[t], 0, 0, 0);
            acc3[t] = __builtin_amdgcn_mfma_f32_16x16x32_f16(al, bh, acc3[t], 0, 0, 0);
        }
    }

    #pragma unroll
    for (int t = 0; t < 4; ++t) {
        int a = (w & 1) * 64 + t * 16 + lr;
        float bx = (w < 2) ? bm[a] : bv[a];
        #pragma unroll
        for (int r = 0; r < 4; ++r) {
            float v = acc3[t][r] + bx;
            size_t row = rowbase + 4 * lg + r;
            if (w < 2) MT[row * ACT + a] = v;
            else       VT[row * ACT + a] = fabsf(v);
        }
    }
}

__global__ __launch_bounds__(256) void k_action(
    const float* __restrict__ MT, const float* __restrict__ VT,
    const float* __restrict__ noise, float* __restrict__ out)
{
    int gid = blockIdx.x*256 + threadIdx.x;
    int a = gid & 127;
    int m = gid >> 7;
    int s  = m % 12;
    int bn = m / 12;
    int n = bn % 31;
    int b = bn / 31;
    int r1 = (b*32 + n)*12 + s;
    int r2 = r1 + 12;
    float m1 = MT[(size_t)r1*ACT + a], m2 = MT[(size_t)r2*ACT + a];
    float v1 = VT[(size_t)r1*ACT + a], v2 = VT[(size_t)r2*ACT + a];
    float adm = m2 - m1;
    float adv = v2 + v1;
    float nz = noise[gid];
    float z = nz * sqrtf(adv + 1e-6f) + adm;
    size_t adbase = ((((size_t)(b*31 + n)*2 + 0)*12 + s)*ACT) + a;
    out[OFF_AD + adbase] = adm;
    out[OFF_AD + adbase + 12*ACT] = adv;
    out[OFF_Z + gid] = z;
}

__global__ __launch_bounds__(256) void k_vq_part(
    const float* __restrict__ Zg, const float* __restrict__ CB,
    float* __restrict__ pval, int* __restrict__ pidx)
{
    __shared__ float Zs[64][128];
    __shared__ float CsT[128][64];

    const int bi = blockIdx.x;
    const int rb = bi >> 4;
    const int cb = bi & 15;
    const int tid = threadIdx.x;

    {
        const float4* zsrc = (const float4*)(Zg + (size_t)rb*64*ACT);
        float4* zd = (float4*)&Zs[0][0];
        #pragma unroll
        for (int j = 0; j < 64*ACT/4/256; ++j)
            zd[tid + 256*j] = zsrc[tid + 256*j];
    }
    #pragma unroll
    for (int j = 0; j < 64*ACT/4/256; ++j) {
        int i = tid + 256*j;
        int c = i & 63;
        int kq = i >> 6;
        float4 v = *(const float4*)&CB[(size_t)(cb*64 + c)*ACT + kq*4];
        CsT[kq*4+0][c] = v.x; CsT[kq*4+1][c] = v.y;
        CsT[kq*4+2][c] = v.z; CsT[kq*4+3][c] = v.w;
    }
    __syncthreads();

    const int rg = tid >> 4;
    const int cg = tid & 15;
    float dot[4][4];
    float cn[4] = {0.f, 0.f, 0.f, 0.f};
    #pragma unroll
    for (int i = 0; i < 4; ++i)
        #pragma unroll
        for (int j = 0; j < 4; ++j) dot[i][j] = 0.f;

    for (int k = 0; k < ACT; k += 4) {
        float4 zv[4];
        #pragma unroll
        for (int i = 0; i < 4; ++i) zv[i] = *(const float4*)&Zs[rg*4 + i][k];
        float4 cv[4];
        #pragma unroll
        for (int kk = 0; kk < 4; ++kk) cv[kk] = *(const float4*)&CsT[k + kk][cg*4];
        #pragma unroll
        for (int kk = 0; kk < 4; ++kk) {
            float4 c4 = cv[kk];
            cn[0] = fmaf(c4.x, c4.x, cn[0]);
            cn[1] = fmaf(c4.y, c4.y, cn[1]);
            cn[2] = fmaf(c4.z, c4.z, cn[2]);
            cn[3] = fmaf(c4.w, c4.w, cn[3]);
            #pragma unroll
            for (int i = 0; i < 4; ++i) {
                float zz = ((const float*)&zv[i])[kk];
                dot[i][0] = fmaf(zz, c4.x, dot[i][0]);
                dot[i][1] = fmaf(zz, c4.y, dot[i][1]);
                dot[i][2] = fmaf(zz, c4.z, dot[i][2]);
                dot[i][3] = fmaf(zz, c4.w, dot[i][3]);
            }
        }
    }

    #pragma unroll
    for (int i = 0; i < 4; ++i) {
        float best = cn[0] - 2.f*dot[i][0];
        int bidx = cb*64 + cg*4;
        #pragma unroll
        for (int j = 1; j < 4; ++j) {
            float d = cn[j] - 2.f*dot[i][j];
            int gi = cb*64 + cg*4 + j;
            if (d < best) { best = d; bidx = gi; }
        }
        #pragma unroll
        for (int off = 1; off < 16; off <<= 1) {
            float ov = __shfl_xor(best, off, 64);
            int   oi = __shfl_xor(bidx, off, 64);
            if (ov < best || (ov == best && oi < bidx)) { best = ov; bidx = oi; }
        }
        if (cg == 0) {
            size_t m = (size_t)rb*64 + rg*4 + i;
            pval[m*16 + cb] = best;
            pidx[m*16 + cb] = bidx;
        }
    }
}

__global__ __launch_bounds__(256) void k_finalize(
    const float* __restrict__ pval, const int* __restrict__ pidx,
    const float* __restrict__ CB, float* __restrict__ out, float* __restrict__ losss)
{
    __shared__ int idx_s[2];
    __shared__ float red[4];
    const int t = threadIdx.x;
    const int half = t >> 7;
    const int a = t & 127;
    const size_t m = (size_t)blockIdx.x*2 + half;

    if (a == 0) {
        const float* pv = &pval[m*16];
        const int*   pi = &pidx[m*16];
        float best = pv[0]; int bi = pi[0];
        for (int i = 1; i < 16; ++i) {
            float v = pv[i]; int ii = pi[i];
            if (v < best || (v == best && ii < bi)) { best = v; bi = ii; }
        }
        idx_s[half] = bi;
        out[OFF_IDX + m] = (float)bi;
    }
    __syncthreads();

    int ci = idx_s[half];
    float q = CB[(size_t)ci*ACT + a];
    float z = out[OFF_Z + m*ACT + a];
    float diff = z - q;
    out[OFF_QS + m*ACT + a] = z + (q - z);
    out[OFF_AV + m*ACT + a] = diff;

    float ls = diff*diff;
    #pragma unroll
    for (int off = 32; off; off >>= 1) ls += __shfl_xor(ls, off, 64);
    if ((t & 63) == 0) red[t >> 6] = ls;
    __syncthreads();
    if (t == 0) atomicAdd(losss, red[0] + red[1] + red[2] + red[3]);
}

__global__ void k_init(float* losss) { *losss = 0.f; }

__global__ void k_losses(const float* __restrict__ losss, float* __restrict__ out)
{
    float v = *losss * (1.f / 6094848.f);
    out[OFF_QL] = v;
    out[OFF_CL] = v;
}

extern "C" void kernel_launch(void* const* d_in, const int* in_sizes, int n_in,
                              void* d_out, int out_size, void* d_ws, size_t ws_size,
                              hipStream_t stream)
{
    const float* slots = (const float*)d_in[0];
    const float* noise = (const float*)d_in[1];
    const float* W1    = (const float*)d_in[2];
    const float* b1    = (const float*)d_in[3];
    const float* ln_g  = (const float*)d_in[4];
    const float* ln_b  = (const float*)d_in[5];
    const float* W2    = (const float*)d_in[6];
    const float* b2    = (const float*)d_in[7];
    const float* Wm    = (const float*)d_in[8];
    const float* bm    = (const float*)d_in[9];
    const float* Wv    = (const float*)d_in[10];
    const float* bv    = (const float*)d_in[11];
    const float* CB    = (const float*)d_in[12];
    float* out = (float*)d_out;
    float* ws  = (float*)d_ws;

    float* MT   = ws + WS_MT;
    float* VT   = ws + WS_VT;
    float* pval = ws + WS_PVAL;
    int*   pidx = (int*)(ws + WS_PIDX);
    float* losss = ws + WS_LOSS;

    _Float16* W1h = (_Float16*)(ws + WS_W1H);
    _Float16* W1l = (_Float16*)(ws + WS_W1L);
    _Float16* W2h = (_Float16*)(ws + WS_W2H);
    _Float16* W2l = (_Float16*)(ws + WS_W2L);
    _Float16* Wmh = (_Float16*)(ws + WS_WMH);
    _Float16* Wml = (_Float16*)(ws + WS_WML);
    _Float16* Wvh = (_Float16*)(ws + WS_WVH);
    _Float16* Wvl = (_Float16*)(ws + WS_WVL);

    hipLaunchKernelGGL(k_init, dim3(1), dim3(1), 0, stream, losss);
    // pack weights (one-time per launch; overlaps pval region, consumed before vq writes it)
    hipLaunchKernelGGL(k_pack, dim3(SLOT*HID/256), dim3(256), 0, stream, W1, W1h, W1l, 3, HID);
    hipLaunchKernelGGL(k_pack, dim3(HID*EMB/256), dim3(256), 0, stream, W2, W2h, W2l, 5, EMB);
    hipLaunchKernelGGL(k_pack, dim3(EMB*ACT/256), dim3(256), 0, stream, Wm, Wmh, Wml, 3, ACT);
    hipLaunchKernelGGL(k_pack, dim3(EMB*ACT/256), dim3(256), 0, stream, Wv, Wvh, Wvl, 3, ACT);

    hipLaunchKernelGGL(k_encoder_mfma, dim3(R_ROWS/16), dim3(256), 0, stream,
                       slots, b1, ln_g, ln_b, b2, bm, bv,
                       W1h, W1l, W2h, W2l, Wmh, Wml, Wvh, Wvl, MT, VT);
    hipLaunchKernelGGL(k_action, dim3(M_ROWS*ACT/256), dim3(256), 0, stream,
                       MT, VT, noise, out);
    hipLaunchKernelGGL(k_vq_part, dim3((M_ROWS/64)*16), dim3(256), 0, stream,
                       out + OFF_Z, CB, pval, pidx);
    hipLaunchKernelGGL(k_finalize, dim3(M_ROWS/2), dim3(256), 0, stream,
                       pval, pidx, CB, out, losss);
    hipLaunchKernelGGL(k_losses, dim3(1), dim3(1), 0, stream, losss, out);
}

// Round 4
// 848.737 us; speedup vs baseline: 1.8471x; 1.1531x over previous
//
#include <hip/hip_runtime.h>
#include <math.h>

#define R_ROWS 49152      // B*N*S = 128*32*12
#define HID 1024
#define SLOT 256
#define EMB 256
#define ACT 128
#define NCODE 1024
#define M_ROWS 47616      // B*(N-1)*S = 128*31*12

// output offsets (float elements)
#define OFF_AD 0
#define OFF_Z  12189696
#define OFF_AV 18284544
#define OFF_QS 24379392
#define OFF_IDX 30474240
#define OFF_QL 30521856
#define OFF_CL 30521857

// workspace offsets (float elements) — all regions disjoint
// sizes: MT/VT 6291456 each; W1h/l,W2h/l 131072 each; Wm/Wv h/l 16384 each;
// CBh/CBl 65536 each (1024x128 fp16 = 65536 float-slots); cn 1024;
// pval/pidx 190464 each
#define WS_MT    0
#define WS_VT    6291456
#define WS_W1H  12582912
#define WS_W1L  12713984
#define WS_W2H  12845056
#define WS_W2L  12976128
#define WS_WMH  13107200
#define WS_WML  13123584
#define WS_WVH  13139968
#define WS_WVL  13156352
#define WS_CBH  13172736
#define WS_CBL  13238272
#define WS_CN   13303808
#define WS_PVAL 13304832
#define WS_PIDX 13495296
#define WS_LOSS 13685760

typedef _Float16 f16x8 __attribute__((ext_vector_type(8)));
typedef float f32x4 __attribute__((ext_vector_type(4)));
typedef float f32x16 __attribute__((ext_vector_type(16)));

// Pack a K x N fp32 matrix into 16x16x32 MFMA B-fragment-linear fp16 hi/lo arrays.
// packed[((t*S + s)*64 + l)*8 + j] = W[s*32 + (l>>4)*8 + j][t*16 + (l&15)]
__global__ __launch_bounds__(256) void k_pack(
    const float* __restrict__ W, _Float16* __restrict__ hi, _Float16* __restrict__ lo,
    int lgS, int N)
{
    int p = blockIdx.x * 256 + threadIdx.x;
    int j = p & 7;
    int l = (p >> 3) & 63;
    int q = p >> 9;
    int s = q & ((1 << lgS) - 1);
    int t = q >> lgS;
    int n = t * 16 + (l & 15);
    int k = s * 32 + ((l >> 4) << 3) + j;
    float x = W[(size_t)k * N + n];
    _Float16 h = (_Float16)x;
    hi[p] = h;
    lo[p] = (_Float16)(x - (float)h);
}

// Pack codebook (NCODE x ACT row-major) as B^T fragments for 32x32x16 MFMA.
// packed[((t*8 + s)*64 + l)*8 + j] = CB[t*32 + (l&31)][s*16 + (l>>5)*8 + j]
__global__ __launch_bounds__(256) void k_packcb(
    const float* __restrict__ CB, _Float16* __restrict__ hi, _Float16* __restrict__ lo)
{
    int p = blockIdx.x * 256 + threadIdx.x;   // 1024*128 total
    int j = p & 7;
    int l = (p >> 3) & 63;
    int q = p >> 9;       // t*8+s
    int s = q & 7;
    int t = q >> 3;
    int n = t * 32 + (l & 31);
    int k = s * 16 + ((l >> 5) << 3) + j;
    float x = CB[(size_t)n * ACT + k];
    _Float16 h = (_Float16)x;
    hi[p] = h;
    lo[p] = (_Float16)(x - (float)h);
}

__global__ __launch_bounds__(256) void k_cbnorm(const float* __restrict__ CB, float* __restrict__ cn)
{
    int c = blockIdx.x * 256 + threadIdx.x;   // 1024
    float s = 0.f;
    #pragma unroll
    for (int k = 0; k < ACT; k += 4) {
        float4 v = *(const float4*)&CB[(size_t)c * ACT + k];
        s += v.x*v.x + v.y*v.y + v.z*v.z + v.w*v.w;
    }
    cn[c] = s;
}

__global__ __launch_bounds__(256, 2) void k_encoder_mfma(
    const float* __restrict__ X,
    const float* __restrict__ b1, const float* __restrict__ ln_g, const float* __restrict__ ln_b,
    const float* __restrict__ b2, const float* __restrict__ bm, const float* __restrict__ bv,
    const _Float16* __restrict__ W1h, const _Float16* __restrict__ W1l,
    const _Float16* __restrict__ W2h, const _Float16* __restrict__ W2l,
    const _Float16* __restrict__ Wmh, const _Float16* __restrict__ Wml,
    const _Float16* __restrict__ Wvh, const _Float16* __restrict__ Wvl,
    float* __restrict__ MT, float* __restrict__ VT)
{
    __shared__ _Float16 Hh0[16][1024];   // 32 KB (hi), also aliased for stats + E tile
    __shared__ _Float16 Hh1[16][1024];   // 32 KB (lo)

    const int tid = threadIdx.x;
    const int w  = tid >> 6;
    const int l  = tid & 63;
    const int lr = l & 15;
    const int lg = l >> 4;
    const long rowbase = (long)blockIdx.x * 16;

    f16x8 a0[8], a1[8];
    {
        const float* xrow = X + (rowbase + lr) * SLOT + lg * 8;
        #pragma unroll
        for (int s = 0; s < 8; ++s) {
            float4 xa = *(const float4*)(xrow + 32 * s);
            float4 xb = *(const float4*)(xrow + 32 * s + 4);
            float xv[8] = {xa.x, xa.y, xa.z, xa.w, xb.x, xb.y, xb.z, xb.w};
            #pragma unroll
            for (int e = 0; e < 8; ++e) {
                _Float16 h = (_Float16)xv[e];
                a0[s][e] = h;
                a1[s][e] = (_Float16)(xv[e] - (float)h);
            }
        }
    }

    f32x4 acc[16];
    #pragma unroll
    for (int t = 0; t < 16; ++t) acc[t] = (f32x4){0.f, 0.f, 0.f, 0.f};

    #pragma unroll
    for (int s = 0; s < 8; ++s) {
        #pragma unroll
        for (int t = 0; t < 16; ++t) {
            int tg = w * 16 + t;
            f16x8 bh = *(const f16x8*)(W1h + ((size_t)(tg * 8 + s) * 64 + l) * 8);
            f16x8 bl = *(const f16x8*)(W1l + ((size_t)(tg * 8 + s) * 64 + l) * 8);
            acc[t] = __builtin_amdgcn_mfma_f32_16x16x32_f16(a0[s], bh, acc[t], 0, 0, 0);
            acc[t] = __builtin_amdgcn_mfma_f32_16x16x32_f16(a0[s], bl, acc[t], 0, 0, 0);
            acc[t] = __builtin_amdgcn_mfma_f32_16x16x32_f16(a1[s], bh, acc[t], 0, 0, 0);
        }
    }

    #pragma unroll
    for (int t = 0; t < 16; ++t) {
        float bb = b1[w * 256 + t * 16 + lr];
        #pragma unroll
        for (int r = 0; r < 4; ++r) acc[t][r] = fmaxf(acc[t][r] + bb, 0.f);
    }

    float sum[4] = {0,0,0,0}, sq[4] = {0,0,0,0};
    #pragma unroll
    for (int t = 0; t < 16; ++t)
        #pragma unroll
        for (int r = 0; r < 4; ++r) {
            float v = acc[t][r];
            sum[r] += v; sq[r] = fmaf(v, v, sq[r]);
        }
    #pragma unroll
    for (int off = 1; off < 16; off <<= 1)
        #pragma unroll
        for (int r = 0; r < 4; ++r) {
            sum[r] += __shfl_xor(sum[r], off, 64);
            sq[r]  += __shfl_xor(sq[r],  off, 64);
        }
    float* stat = (float*)&Hh0[0][0];
    if (lr == 0) {
        #pragma unroll
        for (int r = 0; r < 4; ++r) {
            stat[w * 16 + 4 * lg + r]      = sum[r];
            stat[64 + w * 16 + 4 * lg + r] = sq[r];
        }
    }
    __syncthreads();
    float mu[4], rs[4];
    #pragma unroll
    for (int r = 0; r < 4; ++r) {
        int m = 4 * lg + r;
        float s = stat[m] + stat[16 + m] + stat[32 + m] + stat[48 + m];
        float q = stat[64 + m] + stat[80 + m] + stat[96 + m] + stat[112 + m];
        float mmu = s * (1.f / HID);
        float var = q * (1.f / HID) - mmu * mmu;
        mu[r] = mmu;
        rs[r] = 1.f / sqrtf(var + 1e-5f);
    }
    __syncthreads();

    #pragma unroll
    for (int t = 0; t < 16; ++t) {
        int n = w * 256 + t * 16 + lr;
        float g = ln_g[n], be = ln_b[n];
        #pragma unroll
        for (int r = 0; r < 4; ++r) {
            int m = 4 * lg + r;
            float v = (acc[t][r] - mu[r]) * rs[r] * g + be;
            _Float16 h = (_Float16)v;
            _Float16 lo = (_Float16)(v - (float)h);
            int c = n >> 3, jj = n & 7;
            int cs = c ^ (m & 7);
            Hh0[m][cs * 8 + jj] = h;
            Hh1[m][cs * 8 + jj] = lo;
        }
    }
    __syncthreads();

    f32x4 acc2[4];
    #pragma unroll
    for (int t = 0; t < 4; ++t) acc2[t] = (f32x4){0.f, 0.f, 0.f, 0.f};

    #pragma unroll 4
    for (int s = 0; s < 32; ++s) {
        int cs = (4 * s + lg) ^ (lr & 7);
        f16x8 ah = *(const f16x8*)&Hh0[lr][cs * 8];
        f16x8 al = *(const f16x8*)&Hh1[lr][cs * 8];
        #pragma unroll
        for (int t = 0; t < 4; ++t) {
            int tg = w * 4 + t;
            f16x8 bh = *(const f16x8*)(W2h + ((size_t)(tg * 32 + s) * 64 + l) * 8);
            f16x8 bl = *(const f16x8*)(W2l + ((size_t)(tg * 32 + s) * 64 + l) * 8);
            acc2[t] = __builtin_amdgcn_mfma_f32_16x16x32_f16(ah, bh, acc2[t], 0, 0, 0);
            acc2[t] = __builtin_amdgcn_mfma_f32_16x16x32_f16(ah, bl, acc2[t], 0, 0, 0);
            acc2[t] = __builtin_amdgcn_mfma_f32_16x16x32_f16(al, bh, acc2[t], 0, 0, 0);
        }
    }
    __syncthreads();

    _Float16* Es0 = &Hh0[0][0];
    _Float16* Es1 = &Hh0[0][0] + 4096;
    #pragma unroll
    for (int t = 0; t < 4; ++t) {
        int n = w * 64 + t * 16 + lr;
        float bb2 = b2[n];
        #pragma unroll
        for (int r = 0; r < 4; ++r) {
            int m = 4 * lg + r;
            float v = acc2[t][r] + bb2;
            _Float16 h = (_Float16)v;
            _Float16 lo = (_Float16)(v - (float)h);
            int c = n >> 3, jj = n & 7;
            int cs = c ^ (m & 7);
            Es0[m * 256 + cs * 8 + jj] = h;
            Es1[m * 256 + cs * 8 + jj] = lo;
        }
    }
    __syncthreads();

    const _Float16* WXh = (w < 2) ? Wmh : Wvh;
    const _Float16* WXl = (w < 2) ? Wml : Wvl;
    f32x4 acc3[4];
    #pragma unroll
    for (int t = 0; t < 4; ++t) acc3[t] = (f32x4){0.f, 0.f, 0.f, 0.f};

    #pragma unroll
    for (int s = 0; s < 8; ++s) {
        int cs = (4 * s + lg) ^ (lr & 7);
        f16x8 ah = *(const f16x8*)&Es0[lr * 256 + cs * 8];
        f16x8 al = *(const f16x8*)&Es1[lr * 256 + cs * 8];
        #pragma unroll
        for (int t = 0; t < 4; ++t) {
            int tg = (w & 1) * 4 + t;
            f16x8 bh = *(const f16x8*)(WXh + ((size_t)(tg * 8 + s) * 64 + l) * 8);
            f16x8 bl = *(const f16x8*)(WXl + ((size_t)(tg * 8 + s) * 64 + l) * 8);
            acc3[t] = __builtin_amdgcn_mfma_f32_16x16x32_f16(ah, bh, acc3[t], 0, 0, 0);
            acc3[t] = __builtin_amdgcn_mfma_f32_16x16x32_f16(ah, bl, acc3[t], 0, 0, 0);
            acc3[t] = __builtin_amdgcn_mfma_f32_16x16x32_f16(al, bh, acc3[t], 0, 0, 0);
        }
    }

    #pragma unroll
    for (int t = 0; t < 4; ++t) {
        int a = (w & 1) * 64 + t * 16 + lr;
        float bx = (w < 2) ? bm[a] : bv[a];
        #pragma unroll
        for (int r = 0; r < 4; ++r) {
            float v = acc3[t][r] + bx;
            size_t row = rowbase + 4 * lg + r;
            if (w < 2) MT[row * ACT + a] = v;
            else       VT[row * ACT + a] = fabsf(v);
        }
    }
}

__global__ __launch_bounds__(256) void k_action(
    const float* __restrict__ MT, const float* __restrict__ VT,
    const float* __restrict__ noise, float* __restrict__ out)
{
    int gid = blockIdx.x*256 + threadIdx.x;
    int a = gid & 127;
    int m = gid >> 7;
    int s  = m % 12;
    int bn = m / 12;
    int n = bn % 31;
    int b = bn / 31;
    int r1 = (b*32 + n)*12 + s;
    int r2 = r1 + 12;
    float m1 = MT[(size_t)r1*ACT + a], m2 = MT[(size_t)r2*ACT + a];
    float v1 = VT[(size_t)r1*ACT + a], v2 = VT[(size_t)r2*ACT + a];
    float adm = m2 - m1;
    float adv = v2 + v1;
    float nz = noise[gid];
    float z = nz * sqrtf(adv + 1e-6f) + adm;
    size_t adbase = ((((size_t)(b*31 + n)*2 + 0)*12 + s)*ACT) + a;
    out[OFF_AD + adbase] = adm;
    out[OFF_AD + adbase + 12*ACT] = adv;
    out[OFF_Z + gid] = z;
}

// VQ distances via 32x32x16 MFMA (fp16x2 3-pass): d = |c|^2 - 2 z.c
// block: 128 rows x 256 codes; wave: 32 rows x 256 codes
__global__ __launch_bounds__(256, 2) void k_vq_mfma(
    const float* __restrict__ Zg,
    const _Float16* __restrict__ CBh, const _Float16* __restrict__ CBl,
    const float* __restrict__ cn,
    float* __restrict__ pval, int* __restrict__ pidx)
{
    const int tid = threadIdx.x;
    const int w = tid >> 6, l = tid & 63;
    const int bi = blockIdx.x;
    const int rb = bi >> 2, cb = bi & 3;
    const int rowbase = rb * 128 + w * 32;
    const int col = l & 31;
    const int hw = l >> 5;

    // A fragments: z rows, split fp16 hi/lo in-register (same bytes as fp32 read)
    f16x8 a0[8], a1[8];
    {
        const float* zrow = Zg + (size_t)(rowbase + col) * ACT + hw * 8;
        #pragma unroll
        for (int s = 0; s < 8; ++s) {
            float4 xa = *(const float4*)(zrow + 16 * s);
            float4 xb = *(const float4*)(zrow + 16 * s + 4);
            float xv[8] = {xa.x, xa.y, xa.z, xa.w, xb.x, xb.y, xb.z, xb.w};
            #pragma unroll
            for (int e = 0; e < 8; ++e) {
                _Float16 h = (_Float16)xv[e];
                a0[s][e] = h;
                a1[s][e] = (_Float16)(xv[e] - (float)h);
            }
        }
    }

    f32x16 acc[8];
    #pragma unroll
    for (int t = 0; t < 8; ++t)
        #pragma unroll
        for (int r = 0; r < 16; ++r) acc[t][r] = 0.f;

    #pragma unroll
    for (int s = 0; s < 8; ++s) {
        #pragma unroll
        for (int t = 0; t < 8; ++t) {
            int tg = cb * 8 + t;
            f16x8 bh = *(const f16x8*)(CBh + ((size_t)(tg * 8 + s) * 64 + l) * 8);
            f16x8 bl = *(const f16x8*)(CBl + ((size_t)(tg * 8 + s) * 64 + l) * 8);
            acc[t] = __builtin_amdgcn_mfma_f32_32x32x16_f16(a0[s], bh, acc[t], 0, 0, 0);
            acc[t] = __builtin_amdgcn_mfma_f32_32x32x16_f16(a0[s], bl, acc[t], 0, 0, 0);
            acc[t] = __builtin_amdgcn_mfma_f32_32x32x16_f16(a1[s], bh, acc[t], 0, 0, 0);
        }
    }

    float cnv[8];
    #pragma unroll
    for (int t = 0; t < 8; ++t) cnv[t] = cn[(cb * 8 + t) * 32 + col];

    // C layout 32x32: col = lane&31, row = (reg&3) + 8*(reg>>2) + 4*(lane>>5)
    #pragma unroll
    for (int reg = 0; reg < 16; ++reg) {
        int m = rowbase + (reg & 3) + 8 * (reg >> 2) + 4 * hw;
        float best = cnv[0] - 2.f * acc[0][reg];
        int bidx = cb * 256 + col;
        #pragma unroll
        for (int t = 1; t < 8; ++t) {
            float d = cnv[t] - 2.f * acc[t][reg];
            int gi = cb * 256 + t * 32 + col;
            if (d < best) { best = d; bidx = gi; }
        }
        #pragma unroll
        for (int off = 1; off < 32; off <<= 1) {
            float ov = __shfl_xor(best, off, 64);
            int   oi = __shfl_xor(bidx, off, 64);
            if (ov < best || (ov == best && oi < bidx)) { best = ov; bidx = oi; }
        }
        if (col == 0) {
            pval[(size_t)m * 4 + cb] = best;
            pidx[(size_t)m * 4 + cb] = bidx;
        }
    }
}

__global__ __launch_bounds__(256) void k_finalize(
    const float* __restrict__ pval, const int* __restrict__ pidx,
    const float* __restrict__ CB, float* __restrict__ out, float* __restrict__ losss)
{
    __shared__ int idx_s[2];
    __shared__ float red[4];
    const int t = threadIdx.x;
    const int half = t >> 7;
    const int a = t & 127;
    const size_t m = (size_t)blockIdx.x*2 + half;

    if (a == 0) {
        const float* pv = &pval[m*4];
        const int*   pi = &pidx[m*4];
        float best = pv[0]; int bi = pi[0];
        for (int i = 1; i < 4; ++i) {
            float v = pv[i]; int ii = pi[i];
            if (v < best || (v == best && ii < bi)) { best = v; bi = ii; }
        }
        idx_s[half] = bi;
        out[OFF_IDX + m] = (float)bi;
    }
    __syncthreads();

    int ci = idx_s[half];
    float q = CB[(size_t)ci*ACT + a];
    float z = out[OFF_Z + m*ACT + a];
    float diff = z - q;
    out[OFF_QS + m*ACT + a] = z + (q - z);
    out[OFF_AV + m*ACT + a] = diff;

    float ls = diff*diff;
    #pragma unroll
    for (int off = 32; off; off >>= 1) ls += __shfl_xor(ls, off, 64);
    if ((t & 63) == 0) red[t >> 6] = ls;
    __syncthreads();
    if (t == 0) atomicAdd(losss, red[0] + red[1] + red[2] + red[3]);
}

__global__ void k_init(float* losss) { *losss = 0.f; }

__global__ void k_losses(const float* __restrict__ losss, float* __restrict__ out)
{
    float v = *losss * (1.f / 6094848.f);
    out[OFF_QL] = v;
    out[OFF_CL] = v;
}

extern "C" void kernel_launch(void* const* d_in, const int* in_sizes, int n_in,
                              void* d_out, int out_size, void* d_ws, size_t ws_size,
                              hipStream_t stream)
{
    const float* slots = (const float*)d_in[0];
    const float* noise = (const float*)d_in[1];
    const float* W1    = (const float*)d_in[2];
    const float* b1    = (const float*)d_in[3];
    const float* ln_g  = (const float*)d_in[4];
    const float* ln_b  = (const float*)d_in[5];
    const float* W2    = (const float*)d_in[6];
    const float* b2    = (const float*)d_in[7];
    const float* Wm    = (const float*)d_in[8];
    const float* bm    = (const float*)d_in[9];
    const float* Wv    = (const float*)d_in[10];
    const float* bv    = (const float*)d_in[11];
    const float* CB    = (const float*)d_in[12];
    float* out = (float*)d_out;
    float* ws  = (float*)d_ws;

    float* MT   = ws + WS_MT;
    float* VT   = ws + WS_VT;
    float* pval = ws + WS_PVAL;
    int*   pidx = (int*)(ws + WS_PIDX);
    float* cn   = ws + WS_CN;
    float* losss = ws + WS_LOSS;

    _Float16* W1h = (_Float16*)(ws + WS_W1H);
    _Float16* W1l = (_Float16*)(ws + WS_W1L);
    _Float16* W2h = (_Float16*)(ws + WS_W2H);
    _Float16* W2l = (_Float16*)(ws + WS_W2L);
    _Float16* Wmh = (_Float16*)(ws + WS_WMH);
    _Float16* Wml = (_Float16*)(ws + WS_WML);
    _Float16* Wvh = (_Float16*)(ws + WS_WVH);
    _Float16* Wvl = (_Float16*)(ws + WS_WVL);
    _Float16* CBh = (_Float16*)(ws + WS_CBH);
    _Float16* CBl = (_Float16*)(ws + WS_CBL);

    hipLaunchKernelGGL(k_init, dim3(1), dim3(1), 0, stream, losss);
    hipLaunchKernelGGL(k_pack, dim3(SLOT*HID/256), dim3(256), 0, stream, W1, W1h, W1l, 3, HID);
    hipLaunchKernelGGL(k_pack, dim3(HID*EMB/256), dim3(256), 0, stream, W2, W2h, W2l, 5, EMB);
    hipLaunchKernelGGL(k_pack, dim3(EMB*ACT/256), dim3(256), 0, stream, Wm, Wmh, Wml, 3, ACT);
    hipLaunchKernelGGL(k_pack, dim3(EMB*ACT/256), dim3(256), 0, stream, Wv, Wvh, Wvl, 3, ACT);
    hipLaunchKernelGGL(k_packcb, dim3(NCODE*ACT/256), dim3(256), 0, stream, CB, CBh, CBl);
    hipLaunchKernelGGL(k_cbnorm, dim3(NCODE/256), dim3(256), 0, stream, CB, cn);

    hipLaunchKernelGGL(k_encoder_mfma, dim3(R_ROWS/16), dim3(256), 0, stream,
                       slots, b1, ln_g, ln_b, b2, bm, bv,
                       W1h, W1l, W2h, W2l, Wmh, Wml, Wvh, Wvl, MT, VT);
    hipLaunchKernelGGL(k_action, dim3(M_ROWS*ACT/256), dim3(256), 0, stream,
                       MT, VT, noise, out);
    hipLaunchKernelGGL(k_vq_mfma, dim3((M_ROWS/128)*4), dim3(256), 0, stream,
                       out + OFF_Z, CBh, CBl, cn, pval, pidx);
    hipLaunchKernelGGL(k_finalize, dim3(M_ROWS/2), dim3(256), 0, stream,
                       pval, pidx, CB, out, losss);
    hipLaunchKernelGGL(k_losses, dim3(1), dim3(1), 0, stream, losss, out);
}

// Round 5
// 447.372 us; speedup vs baseline: 3.5043x; 1.8972x over previous
//
#include <hip/hip_runtime.h>
#include <math.h>

#define R_ROWS 49152      // B*N*S = 128*32*12
#define HID 1024
#define SLOT 256
#define EMB 256
#define ACT 128
#define NCODE 1024
#define M_ROWS 47616      // B*(N-1)*S = 128*31*12

// output offsets (float elements)
#define OFF_AD 0
#define OFF_Z  12189696
#define OFF_AV 18284544
#define OFF_QS 24379392
#define OFF_IDX 30474240
#define OFF_QL 30521856
#define OFF_CL 30521857

// workspace offsets (float elements) — all regions disjoint
#define WS_MT    0
#define WS_VT    6291456
#define WS_W1H  12582912
#define WS_W1L  12713984
#define WS_W2H  12845056
#define WS_W2L  12976128
#define WS_WMH  13107200
#define WS_WML  13123584
#define WS_WVH  13139968
#define WS_WVL  13156352
#define WS_CBH  13172736
#define WS_CBL  13238272
#define WS_CN   13303808
#define WS_LOSS 13304832

typedef _Float16 f16x8 __attribute__((ext_vector_type(8)));
typedef float f32x4 __attribute__((ext_vector_type(4)));
typedef float f32x16 __attribute__((ext_vector_type(16)));

// ---------------- fused pack kernel ----------------
// block ranges: [0,1024) W1 | [1024,2048) W2 | [2048,2176) Wm | [2176,2304) Wv
//               [2304,2816) CB | [2816,2820) cbnorm
__device__ __forceinline__ void pack_body(
    const float* __restrict__ W, _Float16* __restrict__ hi, _Float16* __restrict__ lo,
    int lgS, int N, int p)
{
    int j = p & 7;
    int l = (p >> 3) & 63;
    int q = p >> 9;
    int s = q & ((1 << lgS) - 1);
    int t = q >> lgS;
    int n = t * 16 + (l & 15);
    int k = s * 32 + ((l >> 4) << 3) + j;
    float x = W[(size_t)k * N + n];
    _Float16 h = (_Float16)x;
    hi[p] = h;
    lo[p] = (_Float16)(x - (float)h);
}

__global__ __launch_bounds__(256) void k_packall(
    const float* __restrict__ W1, const float* __restrict__ W2,
    const float* __restrict__ Wm, const float* __restrict__ Wv,
    const float* __restrict__ CB,
    _Float16* __restrict__ W1h, _Float16* __restrict__ W1l,
    _Float16* __restrict__ W2h, _Float16* __restrict__ W2l,
    _Float16* __restrict__ Wmh, _Float16* __restrict__ Wml,
    _Float16* __restrict__ Wvh, _Float16* __restrict__ Wvl,
    _Float16* __restrict__ CBh, _Float16* __restrict__ CBl,
    float* __restrict__ cn, float* __restrict__ losss)
{
    const int bi = blockIdx.x;
    const int tid = threadIdx.x;
    if (bi == 0 && tid == 0) *losss = 0.f;

    if (bi < 1024) {
        pack_body(W1, W1h, W1l, 3, HID, bi * 256 + tid);
    } else if (bi < 2048) {
        pack_body(W2, W2h, W2l, 5, EMB, (bi - 1024) * 256 + tid);
    } else if (bi < 2176) {
        pack_body(Wm, Wmh, Wml, 3, ACT, (bi - 2048) * 256 + tid);
    } else if (bi < 2304) {
        pack_body(Wv, Wvh, Wvl, 3, ACT, (bi - 2176) * 256 + tid);
    } else if (bi < 2816) {
        // codebook pack for 32x32x16 B-fragments:
        // packed[((t*8+s)*64+l)*8+j] = CB[t*32+(l&31)][s*16+(l>>5)*8+j]
        int p = (bi - 2304) * 256 + tid;
        int j = p & 7;
        int l = (p >> 3) & 63;
        int q = p >> 9;
        int s = q & 7;
        int t = q >> 3;
        int n = t * 32 + (l & 31);
        int k = s * 16 + ((l >> 5) << 3) + j;
        float x = CB[(size_t)n * ACT + k];
        _Float16 h = (_Float16)x;
        CBh[p] = h;
        CBl[p] = (_Float16)(x - (float)h);
    } else {
        int c = (bi - 2816) * 256 + tid;   // 0..1023
        float s = 0.f;
        #pragma unroll
        for (int k = 0; k < ACT; k += 4) {
            float4 v = *(const float4*)&CB[(size_t)c * ACT + k];
            s += v.x*v.x + v.y*v.y + v.z*v.z + v.w*v.w;
        }
        cn[c] = s;
    }
}

// ---------------- encoder: 512 threads / 8 waves, 16 rows/block ----------------
__global__ __launch_bounds__(512, 4) void k_encoder_mfma(
    const float* __restrict__ X,
    const float* __restrict__ b1, const float* __restrict__ ln_g, const float* __restrict__ ln_b,
    const float* __restrict__ b2, const float* __restrict__ bm, const float* __restrict__ bv,
    const _Float16* __restrict__ W1h, const _Float16* __restrict__ W1l,
    const _Float16* __restrict__ W2h, const _Float16* __restrict__ W2l,
    const _Float16* __restrict__ Wmh, const _Float16* __restrict__ Wml,
    const _Float16* __restrict__ Wvh, const _Float16* __restrict__ Wvl,
    float* __restrict__ MT, float* __restrict__ VT)
{
    __shared__ _Float16 Hh0[16][1024];   // 32 KB (hi); aliased for stats + E tile
    __shared__ _Float16 Hh1[16][1024];   // 32 KB (lo)

    const int tid = threadIdx.x;
    const int w  = tid >> 6;      // 0..7
    const int l  = tid & 63;
    const int lr = l & 15;
    const int lg = l >> 4;
    const long rowbase = (long)blockIdx.x * 16;

    // A fragments: 16 rows x 256 k, fp16 hi/lo (same for all waves)
    f16x8 a0[8], a1[8];
    {
        const float* xrow = X + (rowbase + lr) * SLOT + lg * 8;
        #pragma unroll
        for (int s = 0; s < 8; ++s) {
            float4 xa = *(const float4*)(xrow + 32 * s);
            float4 xb = *(const float4*)(xrow + 32 * s + 4);
            float xv[8] = {xa.x, xa.y, xa.z, xa.w, xb.x, xb.y, xb.z, xb.w};
            #pragma unroll
            for (int e = 0; e < 8; ++e) {
                _Float16 h = (_Float16)xv[e];
                a0[s][e] = h;
                a1[s][e] = (_Float16)(xv[e] - (float)h);
            }
        }
    }

    // GEMM1: wave w owns H cols [128w, 128w+128)
    f32x4 acc[8];
    #pragma unroll
    for (int t = 0; t < 8; ++t) acc[t] = (f32x4){0.f, 0.f, 0.f, 0.f};

    #pragma unroll
    for (int s = 0; s < 8; ++s) {
        #pragma unroll
        for (int t = 0; t < 8; ++t) {
            int tg = w * 8 + t;
            f16x8 bh = *(const f16x8*)(W1h + ((size_t)(tg * 8 + s) * 64 + l) * 8);
            f16x8 bl = *(const f16x8*)(W1l + ((size_t)(tg * 8 + s) * 64 + l) * 8);
            acc[t] = __builtin_amdgcn_mfma_f32_16x16x32_f16(a0[s], bh, acc[t], 0, 0, 0);
            acc[t] = __builtin_amdgcn_mfma_f32_16x16x32_f16(a0[s], bl, acc[t], 0, 0, 0);
            acc[t] = __builtin_amdgcn_mfma_f32_16x16x32_f16(a1[s], bh, acc[t], 0, 0, 0);
        }
    }

    // bias + ReLU
    #pragma unroll
    for (int t = 0; t < 8; ++t) {
        float bb = b1[w * 128 + t * 16 + lr];
        #pragma unroll
        for (int r = 0; r < 4; ++r) acc[t][r] = fmaxf(acc[t][r] + bb, 0.f);
    }

    // LayerNorm stats: per-wave partials, 16-lane shuffle, cross-wave via LDS
    float sum[4] = {0,0,0,0}, sq[4] = {0,0,0,0};
    #pragma unroll
    for (int t = 0; t < 8; ++t)
        #pragma unroll
        for (int r = 0; r < 4; ++r) {
            float v = acc[t][r];
            sum[r] += v; sq[r] = fmaf(v, v, sq[r]);
        }
    #pragma unroll
    for (int off = 1; off < 16; off <<= 1)
        #pragma unroll
        for (int r = 0; r < 4; ++r) {
            sum[r] += __shfl_xor(sum[r], off, 64);
            sq[r]  += __shfl_xor(sq[r],  off, 64);
        }
    float* stat = (float*)&Hh0[0][0];   // [0..127]=sum, [128..255]=sq
    if (lr == 0) {
        #pragma unroll
        for (int r = 0; r < 4; ++r) {
            stat[w * 16 + 4 * lg + r]       = sum[r];
            stat[128 + w * 16 + 4 * lg + r] = sq[r];
        }
    }
    __syncthreads();
    float mu[4], rs[4];
    #pragma unroll
    for (int r = 0; r < 4; ++r) {
        int m = 4 * lg + r;
        float s = 0.f, q = 0.f;
        #pragma unroll
        for (int wv = 0; wv < 8; ++wv) {
            s += stat[wv * 16 + m];
            q += stat[128 + wv * 16 + m];
        }
        float mmu = s * (1.f / HID);
        float var = q * (1.f / HID) - mmu * mmu;
        mu[r] = mmu;
        rs[r] = 1.f / sqrtf(var + 1e-5f);
    }
    __syncthreads();

    // normalize, split, store swizzled
    #pragma unroll
    for (int t = 0; t < 8; ++t) {
        int n = w * 128 + t * 16 + lr;
        float g = ln_g[n], be = ln_b[n];
        #pragma unroll
        for (int r = 0; r < 4; ++r) {
            int m = 4 * lg + r;
            float v = (acc[t][r] - mu[r]) * rs[r] * g + be;
            _Float16 h = (_Float16)v;
            _Float16 lo = (_Float16)(v - (float)h);
            int c = n >> 3, jj = n & 7;
            int cs = c ^ (m & 7);
            Hh0[m][cs * 8 + jj] = h;
            Hh1[m][cs * 8 + jj] = lo;
        }
    }
    __syncthreads();

    // GEMM2: wave w owns E cols [32w, 32w+32)
    f32x4 acc2[2];
    #pragma unroll
    for (int t = 0; t < 2; ++t) acc2[t] = (f32x4){0.f, 0.f, 0.f, 0.f};

    #pragma unroll 4
    for (int s = 0; s < 32; ++s) {
        int cs = (4 * s + lg) ^ (lr & 7);
        f16x8 ah = *(const f16x8*)&Hh0[lr][cs * 8];
        f16x8 al = *(const f16x8*)&Hh1[lr][cs * 8];
        #pragma unroll
        for (int t = 0; t < 2; ++t) {
            int tg = w * 2 + t;
            f16x8 bh = *(const f16x8*)(W2h + ((size_t)(tg * 32 + s) * 64 + l) * 8);
            f16x8 bl = *(const f16x8*)(W2l + ((size_t)(tg * 32 + s) * 64 + l) * 8);
            acc2[t] = __builtin_amdgcn_mfma_f32_16x16x32_f16(ah, bh, acc2[t], 0, 0, 0);
            acc2[t] = __builtin_amdgcn_mfma_f32_16x16x32_f16(ah, bl, acc2[t], 0, 0, 0);
            acc2[t] = __builtin_amdgcn_mfma_f32_16x16x32_f16(al, bh, acc2[t], 0, 0, 0);
        }
    }
    __syncthreads();

    // E tile (+b2) -> fp16x2, swizzled, aliased into Hh0
    _Float16* Es0 = &Hh0[0][0];          // 16x256
    _Float16* Es1 = &Hh0[0][0] + 4096;   // 16x256
    #pragma unroll
    for (int t = 0; t < 2; ++t) {
        int n = w * 32 + t * 16 + lr;
        float bb2 = b2[n];
        #pragma unroll
        for (int r = 0; r < 4; ++r) {
            int m = 4 * lg + r;
            float v = acc2[t][r] + bb2;
            _Float16 h = (_Float16)v;
            _Float16 lo = (_Float16)(v - (float)h);
            int c = n >> 3, jj = n & 7;
            int cs = c ^ (m & 7);
            Es0[m * 256 + cs * 8 + jj] = h;
            Es1[m * 256 + cs * 8 + jj] = lo;
        }
    }
    __syncthreads();

    // heads: waves 0..3 -> MT cols 32(w&3).., waves 4..7 -> VT
    const _Float16* WXh = (w < 4) ? Wmh : Wvh;
    const _Float16* WXl = (w < 4) ? Wml : Wvl;
    f32x4 acc3[2];
    #pragma unroll
    for (int t = 0; t < 2; ++t) acc3[t] = (f32x4){0.f, 0.f, 0.f, 0.f};

    #pragma unroll
    for (int s = 0; s < 8; ++s) {
        int cs = (4 * s + lg) ^ (lr & 7);
        f16x8 ah = *(const f16x8*)&Es0[lr * 256 + cs * 8];
        f16x8 al = *(const f16x8*)&Es1[lr * 256 + cs * 8];
        #pragma unroll
        for (int t = 0; t < 2; ++t) {
            int tg = (w & 3) * 2 + t;
            f16x8 bh = *(const f16x8*)(WXh + ((size_t)(tg * 8 + s) * 64 + l) * 8);
            f16x8 bl = *(const f16x8*)(WXl + ((size_t)(tg * 8 + s) * 64 + l) * 8);
            acc3[t] = __builtin_amdgcn_mfma_f32_16x16x32_f16(ah, bh, acc3[t], 0, 0, 0);
            acc3[t] = __builtin_amdgcn_mfma_f32_16x16x32_f16(ah, bl, acc3[t], 0, 0, 0);
            acc3[t] = __builtin_amdgcn_mfma_f32_16x16x32_f16(al, bh, acc3[t], 0, 0, 0);
        }
    }

    #pragma unroll
    for (int t = 0; t < 2; ++t) {
        int a = (w & 3) * 32 + t * 16 + lr;
        float bx = (w < 4) ? bm[a] : bv[a];
        #pragma unroll
        for (int r = 0; r < 4; ++r) {
            float v = acc3[t][r] + bx;
            size_t row = rowbase + 4 * lg + r;
            if (w < 4) MT[row * ACT + a] = v;
            else       VT[row * ACT + a] = fabsf(v);
        }
    }
}

// ---------------- fused action + VQ + finalize ----------------
// 372 blocks x 256 threads; each block owns 128 consecutive m-rows.
__global__ __launch_bounds__(256, 2) void k_vqfused(
    const float* __restrict__ MT, const float* __restrict__ VT,
    const float* __restrict__ noise,
    const _Float16* __restrict__ CBh, const _Float16* __restrict__ CBl,
    const float* __restrict__ cn, const float* __restrict__ CB,
    float* __restrict__ out, float* __restrict__ losss)
{
    __shared__ float4 Zs4[4096];         // 64 KB: z[128][128], XOR-swizzled float4s
    __shared__ int   idx_s[128];
    __shared__ float red[4];
    float* Zs = (float*)Zs4;

    const int tid = threadIdx.x;
    const int rowbase = blockIdx.x * 128;
    const int a = tid & 127;
    const int rhalf = tid >> 7;

    // ---- phase 1: z = noise*sqrt(adv+eps)+adm; write AD + Z outputs; stash z in LDS ----
    #pragma unroll 8
    for (int i = 0; i < 64; ++i) {
        int row = 2 * i + rhalf;
        int m = rowbase + row;
        int b = m / 372;
        int r1 = m + 12 * b;
        int r2 = r1 + 12;
        float m1 = MT[(size_t)r1 * ACT + a], m2 = MT[(size_t)r2 * ACT + a];
        float v1 = VT[(size_t)r1 * ACT + a], v2 = VT[(size_t)r2 * ACT + a];
        float adm = m2 - m1;
        float adv = v2 + v1;
        float z = noise[(size_t)m * ACT + a] * sqrtf(adv + 1e-6f) + adm;
        int np = m / 12, s = m - np * 12;
        out[OFF_AD + (size_t)(np * 24 + s) * ACT + a] = adm;
        out[OFF_AD + (size_t)(np * 24 + 12 + s) * ACT + a] = adv;
        out[OFF_Z + (size_t)m * ACT + a] = z;
        Zs[row * 128 + (((a >> 2) ^ (row & 31)) << 2) + (a & 3)] = z;
    }
    __syncthreads();

    // ---- phase 2: A fragments from LDS (wave w owns rows [32w,32w+32)) ----
    const int w = tid >> 6, l = tid & 63;
    const int col = l & 31, hw = l >> 5;
    const int arow = 32 * w + col;

    f16x8 a0[8], a1[8];
    #pragma unroll
    for (int s = 0; s < 8; ++s) {
        #pragma unroll
        for (int half = 0; half < 2; ++half) {
            int k4 = s * 4 + hw * 2 + half;   // float4 index along k
            float4 v = *(const float4*)&Zs[arow * 128 + ((k4 ^ (arow & 31)) << 2)];
            float xv[4] = {v.x, v.y, v.z, v.w};
            #pragma unroll
            for (int e = 0; e < 4; ++e) {
                _Float16 h = (_Float16)xv[e];
                a0[s][half * 4 + e] = h;
                a1[s][half * 4 + e] = (_Float16)(xv[e] - (float)h);
            }
        }
    }

    // ---- phase 3: distances over 4 codebook chunks, running argmin ----
    float best[16];
    int bidx[16];
    #pragma unroll
    for (int r = 0; r < 16; ++r) { best[r] = 3.4e38f; bidx[r] = 0; }

    for (int cb = 0; cb < 4; ++cb) {
        f32x16 acc[8];
        #pragma unroll
        for (int t = 0; t < 8; ++t)
            #pragma unroll
            for (int r = 0; r < 16; ++r) acc[t][r] = 0.f;

        #pragma unroll
        for (int s = 0; s < 8; ++s) {
            #pragma unroll
            for (int t = 0; t < 8; ++t) {
                int tg = cb * 8 + t;
                f16x8 bh = *(const f16x8*)(CBh + ((size_t)(tg * 8 + s) * 64 + l) * 8);
                f16x8 bl = *(const f16x8*)(CBl + ((size_t)(tg * 8 + s) * 64 + l) * 8);
                acc[t] = __builtin_amdgcn_mfma_f32_32x32x16_f16(a0[s], bh, acc[t], 0, 0, 0);
                acc[t] = __builtin_amdgcn_mfma_f32_32x32x16_f16(a0[s], bl, acc[t], 0, 0, 0);
                acc[t] = __builtin_amdgcn_mfma_f32_32x32x16_f16(a1[s], bh, acc[t], 0, 0, 0);
            }
        }

        float cnv[8];
        #pragma unroll
        for (int t = 0; t < 8; ++t) cnv[t] = cn[cb * 256 + t * 32 + col];

        #pragma unroll
        for (int reg = 0; reg < 16; ++reg) {
            #pragma unroll
            for (int t = 0; t < 8; ++t) {
                float d = cnv[t] - 2.f * acc[t][reg];
                int gi = cb * 256 + t * 32 + col;
                if (d < best[reg]) { best[reg] = d; bidx[reg] = gi; }
            }
        }
    }

    // reduce over the 32 cols; C row = (reg&3)+8*(reg>>2)+4*hw
    #pragma unroll
    for (int reg = 0; reg < 16; ++reg) {
        float bv_ = best[reg];
        int bi_ = bidx[reg];
        #pragma unroll
        for (int off = 1; off < 32; off <<= 1) {
            float ov = __shfl_xor(bv_, off, 64);
            int   oi = __shfl_xor(bi_, off, 64);
            if (ov < bv_ || (ov == bv_ && oi < bi_)) { bv_ = ov; bi_ = oi; }
        }
        if (col == 0) {
            int mloc = 32 * w + (reg & 3) + 8 * (reg >> 2) + 4 * hw;
            idx_s[mloc] = bi_;
            out[OFF_IDX + rowbase + mloc] = (float)bi_;
        }
    }
    __syncthreads();

    // ---- phase 4: gather q, write QS/AV, block loss ----
    float ls = 0.f;
    #pragma unroll 8
    for (int i = 0; i < 64; ++i) {
        int row = 2 * i + rhalf;
        float z = Zs[row * 128 + (((a >> 2) ^ (row & 31)) << 2) + (a & 3)];
        int ci = idx_s[row];
        float q = CB[(size_t)ci * ACT + a];
        float diff = z - q;
        size_t m = (size_t)(rowbase + row);
        out[OFF_QS + m * ACT + a] = z + (q - z);
        out[OFF_AV + m * ACT + a] = diff;
        ls = fmaf(diff, diff, ls);
    }
    #pragma unroll
    for (int off = 32; off; off >>= 1) ls += __shfl_xor(ls, off, 64);
    if (l == 0) red[w] = ls;
    __syncthreads();
    if (tid == 0) atomicAdd(losss, red[0] + red[1] + red[2] + red[3]);
}

__global__ void k_losses(const float* __restrict__ losss, float* __restrict__ out)
{
    float v = *losss * (1.f / 6094848.f);
    out[OFF_QL] = v;
    out[OFF_CL] = v;
}

extern "C" void kernel_launch(void* const* d_in, const int* in_sizes, int n_in,
                              void* d_out, int out_size, void* d_ws, size_t ws_size,
                              hipStream_t stream)
{
    const float* slots = (const float*)d_in[0];
    const float* noise = (const float*)d_in[1];
    const float* W1    = (const float*)d_in[2];
    const float* b1    = (const float*)d_in[3];
    const float* ln_g  = (const float*)d_in[4];
    const float* ln_b  = (const float*)d_in[5];
    const float* W2    = (const float*)d_in[6];
    const float* b2    = (const float*)d_in[7];
    const float* Wm    = (const float*)d_in[8];
    const float* bm    = (const float*)d_in[9];
    const float* Wv    = (const float*)d_in[10];
    const float* bv    = (const float*)d_in[11];
    const float* CB    = (const float*)d_in[12];
    float* out = (float*)d_out;
    float* ws  = (float*)d_ws;

    float* MT   = ws + WS_MT;
    float* VT   = ws + WS_VT;
    float* cn   = ws + WS_CN;
    float* losss = ws + WS_LOSS;

    _Float16* W1h = (_Float16*)(ws + WS_W1H);
    _Float16* W1l = (_Float16*)(ws + WS_W1L);
    _Float16* W2h = (_Float16*)(ws + WS_W2H);
    _Float16* W2l = (_Float16*)(ws + WS_W2L);
    _Float16* Wmh = (_Float16*)(ws + WS_WMH);
    _Float16* Wml = (_Float16*)(ws + WS_WML);
    _Float16* Wvh = (_Float16*)(ws + WS_WVH);
    _Float16* Wvl = (_Float16*)(ws + WS_WVL);
    _Float16* CBh = (_Float16*)(ws + WS_CBH);
    _Float16* CBl = (_Float16*)(ws + WS_CBL);

    hipLaunchKernelGGL(k_packall, dim3(2820), dim3(256), 0, stream,
                       W1, W2, Wm, Wv, CB,
                       W1h, W1l, W2h, W2l, Wmh, Wml, Wvh, Wvl, CBh, CBl, cn, losss);
    hipLaunchKernelGGL(k_encoder_mfma, dim3(R_ROWS/16), dim3(512), 0, stream,
                       slots, b1, ln_g, ln_b, b2, bm, bv,
                       W1h, W1l, W2h, W2l, Wmh, Wml, Wvh, Wvl, MT, VT);
    hipLaunchKernelGGL(k_vqfused, dim3(M_ROWS/128), dim3(256), 0, stream,
                       MT, VT, noise, CBh, CBl, cn, CB, out, losss);
    hipLaunchKernelGGL(k_losses, dim3(1), dim3(1), 0, stream, losss, out);
}